// Round 2
// baseline (26272.580 us; speedup 1.0000x reference)
//
#include <hip/hip_runtime.h>
#include <hip/hip_bf16.h>

// ---------------------------------------------------------------------------
// UNet3D dense forward. Round 2: bf16 intermediate storage (fp32 accumulate)
// to cut d_ws usage from 323MB -> 154MB (suspected ws overflow caused the
// round-1 GPU fault). Direct conv kernels, concats virtual via split inputs.
// ---------------------------------------------------------------------------

using bf16 = __hip_bfloat16;

#define TPB 256

static inline int cdiv_l(long a, int b) { return (int)((a + b - 1) / b); }

__device__ __forceinline__ float toF(float v) { return v; }
__device__ __forceinline__ float toF(bf16 v) { return __bfloat162float(v); }
__device__ __forceinline__ void stV(float* p, float v) { *p = v; }
__device__ __forceinline__ void stV(bf16* p, float v) { *p = __float2bfloat16(v); }

// ---------------- conv3d, pad 1, cubic spatial, OIDHW weights ----------------
template <typename Tin, typename Tout>
__global__ void conv3d_k(const Tin* __restrict__ in, const float* __restrict__ w,
                         Tout* __restrict__ out,
                         int N, int Cin, int Cout, int Din, int Dout, int stride) {
  long total = (long)N * Cout * Dout * Dout * Dout;
  long idx = (long)blockIdx.x * blockDim.x + threadIdx.x;
  if (idx >= total) return;
  int ow = (int)(idx % Dout); long t = idx / Dout;
  int oh = (int)(t % Dout); t /= Dout;
  int od = (int)(t % Dout); t /= Dout;
  int co = (int)(t % Cout);
  int n  = (int)(t / Cout);

  int id0 = od * stride - 1, ih0 = oh * stride - 1, iw0 = ow * stride - 1;
  long sp = (long)Din * Din * Din;
  const Tin* inN = in + (long)n * Cin * sp;
  const float* wC = w + (long)co * Cin * 27;
  float acc = 0.f;
  for (int ci = 0; ci < Cin; ++ci) {
    const Tin* ip = inN + (long)ci * sp;
    const float* wp = wC + ci * 27;
#pragma unroll
    for (int kd = 0; kd < 3; ++kd) {
      int id = id0 + kd;
      if ((unsigned)id >= (unsigned)Din) continue;
#pragma unroll
      for (int kh = 0; kh < 3; ++kh) {
        int ih = ih0 + kh;
        if ((unsigned)ih >= (unsigned)Din) continue;
        const Tin* row = ip + ((long)id * Din + ih) * Din;
        const float* wr = wp + (kd * 3 + kh) * 3;
#pragma unroll
        for (int kw = 0; kw < 3; ++kw) {
          int iw = iw0 + kw;
          if ((unsigned)iw >= (unsigned)Din) continue;
          acc += toF(row[iw]) * wr[kw];
        }
      }
    }
  }
  stV(&out[idx], acc);
}

// ---------------- tconv3d stride 2 'SAME' (lhs_dil=2, pad (2,1)), DHWIO -----
// out[o] uses input i = (o+k-2)/2 when (o+k) even and 0<=i<Din. Dout=2*Din.
// Channel-split input: [0,CA) from inA, [CA,CA+CB) from inB (virtual concat).
template <typename Tout>
__global__ void tconv3d_s2_k(const bf16* __restrict__ inA, int CA,
                             const bf16* __restrict__ inB, int CB,
                             const float* __restrict__ w,
                             Tout* __restrict__ out,
                             int N, int Cout, int Din, int Dout) {
  long total = (long)N * Cout * Dout * Dout * Dout;
  long idx = (long)blockIdx.x * blockDim.x + threadIdx.x;
  if (idx >= total) return;
  int ow = (int)(idx % Dout); long t = idx / Dout;
  int oh = (int)(t % Dout); t /= Dout;
  int od = (int)(t % Dout); t /= Dout;
  int co = (int)(t % Cout);
  int n  = (int)(t / Cout);
  int Cin = CA + CB;
  long sp = (long)Din * Din * Din;
  const bf16* baseA = inA + (long)n * CA * sp;
  const bf16* baseB = inB ? inB + (long)n * CB * sp : nullptr;
  float acc = 0.f;
#pragma unroll
  for (int kd = 0; kd < 3; ++kd) {
    if ((od + kd) & 1) continue;
    int id = (od + kd - 2) >> 1;
    if ((unsigned)id >= (unsigned)Din) continue;
#pragma unroll
    for (int kh = 0; kh < 3; ++kh) {
      if ((oh + kh) & 1) continue;
      int ih = (oh + kh - 2) >> 1;
      if ((unsigned)ih >= (unsigned)Din) continue;
#pragma unroll
      for (int kw = 0; kw < 3; ++kw) {
        if ((ow + kw) & 1) continue;
        int iw = (ow + kw - 2) >> 1;
        if ((unsigned)iw >= (unsigned)Din) continue;
        long spOff = ((long)id * Din + ih) * Din + iw;
        const float* wp = w + (long)((kd * 3 + kh) * 3 + kw) * Cin * Cout + co;
        for (int ci = 0; ci < CA; ++ci)
          acc += toF(baseA[(long)ci * sp + spOff]) * wp[(long)ci * Cout];
        for (int ci = 0; ci < CB; ++ci)
          acc += toF(baseB[(long)ci * sp + spOff]) * wp[(long)(CA + ci) * Cout];
      }
    }
  }
  stV(&out[idx], acc);
}

// ---------------- tconv3d stride 1 'SAME' (pad 1), DHWIO, split input -------
template <typename Tout>
__global__ void tconv3d_s1_k(const bf16* __restrict__ inA, int CA,
                             const bf16* __restrict__ inB, int CB,
                             const float* __restrict__ w,
                             Tout* __restrict__ out,
                             int N, int Cout, int Din) {
  int Dout = Din;
  long total = (long)N * Cout * Dout * Dout * Dout;
  long idx = (long)blockIdx.x * blockDim.x + threadIdx.x;
  if (idx >= total) return;
  int ow = (int)(idx % Dout); long t = idx / Dout;
  int oh = (int)(t % Dout); t /= Dout;
  int od = (int)(t % Dout); t /= Dout;
  int co = (int)(t % Cout);
  int n  = (int)(t / Cout);
  int Cin = CA + CB;
  long sp = (long)Din * Din * Din;
  const bf16* baseA = inA + (long)n * CA * sp;
  const bf16* baseB = inB ? inB + (long)n * CB * sp : nullptr;
  float acc = 0.f;
#pragma unroll
  for (int kd = 0; kd < 3; ++kd) {
    int id = od + kd - 1;
    if ((unsigned)id >= (unsigned)Din) continue;
#pragma unroll
    for (int kh = 0; kh < 3; ++kh) {
      int ih = oh + kh - 1;
      if ((unsigned)ih >= (unsigned)Din) continue;
#pragma unroll
      for (int kw = 0; kw < 3; ++kw) {
        int iw = ow + kw - 1;
        if ((unsigned)iw >= (unsigned)Din) continue;
        long spOff = ((long)id * Din + ih) * Din + iw;
        const float* wp = w + (long)((kd * 3 + kh) * 3 + kw) * Cin * Cout + co;
        for (int ci = 0; ci < CA; ++ci)
          acc += toF(baseA[(long)ci * sp + spOff]) * wp[(long)ci * Cout];
        for (int ci = 0; ci < CB; ++ci)
          acc += toF(baseB[(long)ci * sp + spOff]) * wp[(long)(CA + ci) * Cout];
      }
    }
  }
  stV(&out[idx], acc);
}

// ---------------- BN stats: one block per channel ----------------
__global__ void bn_stats_k(const bf16* __restrict__ x, float* __restrict__ mean,
                           float* __restrict__ var, int N, int C, long spatial) {
  int c = blockIdx.x;
  int tid = threadIdx.x;
  float s = 0.f, q = 0.f;
  for (int n = 0; n < N; ++n) {
    const bf16* p = x + ((long)n * C + c) * spatial;
    for (long i = tid; i < spatial; i += blockDim.x) {
      float v = toF(p[i]);
      s += v; q += v * v;
    }
  }
  __shared__ float shs[TPB], shq[TPB];
  shs[tid] = s; shq[tid] = q;
  __syncthreads();
  for (int off = TPB / 2; off > 0; off >>= 1) {
    if (tid < off) { shs[tid] += shs[tid + off]; shq[tid] += shq[tid + off]; }
    __syncthreads();
  }
  if (tid == 0) {
    float cnt = (float)((long)N * spatial);
    float m = shs[0] / cnt;
    mean[c] = m;
    var[c] = shq[0] / cnt - m * m;
  }
}

// ---------------- BN apply + ReLU, in place (bf16) ----------------
__global__ void bn_relu_k(bf16* __restrict__ x, const float* __restrict__ mean,
                          const float* __restrict__ var, const float* __restrict__ g,
                          const float* __restrict__ b, int N, int C, long spatial) {
  long total = (long)N * C * spatial;
  long stride = (long)gridDim.x * blockDim.x;
  for (long idx = (long)blockIdx.x * blockDim.x + threadIdx.x; idx < total; idx += stride) {
    int c = (int)((idx / spatial) % C);
    float rs = rsqrtf(var[c] + 1e-5f);
    float y = (toF(x[idx]) - mean[c]) * rs * g[c] + b[c];
    stV(&x[idx], y > 0.f ? y : 0.f);
  }
}

extern "C" void kernel_launch(void* const* d_in, const int* in_sizes, int n_in,
                              void* d_out, int out_size, void* d_ws, size_t ws_size,
                              hipStream_t stream) {
  const float* x    = (const float*)d_in[0];
  const float* w0   = (const float*)d_in[1];
  const float* g0   = (const float*)d_in[2];
  const float* b0   = (const float*)d_in[3];
  const float* w1   = (const float*)d_in[4];
  const float* g1   = (const float*)d_in[5];
  const float* b1   = (const float*)d_in[6];
  const float* w2   = (const float*)d_in[7];
  const float* g2   = (const float*)d_in[8];
  const float* b2   = (const float*)d_in[9];
  const float* wt2r = (const float*)d_in[10];
  const float* g2r  = (const float*)d_in[11];
  const float* b2r  = (const float*)d_in[12];
  const float* wt1r = (const float*)d_in[13];
  const float* g1r  = (const float*)d_in[14];
  const float* b1r  = (const float*)d_in[15];
  const float* wt0r = (const float*)d_in[16];
  const float* wt2c = (const float*)d_in[17];
  const float* g2c  = (const float*)d_in[18];
  const float* b2c  = (const float*)d_in[19];
  const float* wt1c = (const float*)d_in[20];
  const float* g1c  = (const float*)d_in[21];
  const float* b1c  = (const float*)d_in[22];
  const float* wt0c = (const float*)d_in[23];

  const int N = 2;
  const long sp64 = 64L * 64 * 64;
  const long sp32 = 32L * 32 * 32;
  const long sp16 = 16L * 16 * 16;

  // workspace layout: bf16 activations (2 bytes each), fp32 stats at the end.
  // total = 154MB + 1KB.
  char* wsB = (char*)d_ws;
  bf16* s1  = (bf16*)wsB;                                  // 16,777,216 el (32MB)
  bf16* s2  = s1  + 2L * 32 * sp64;                        //  4,194,304 (8MB)
  bf16* s4  = s2  + 2L * 64 * sp32;                        //  1,048,576 (2MB)
  bf16* r32 = s4  + 2L * 128 * sp16;                       //  4,194,304 (8MB)
  bf16* c32 = r32 + 2L * 64 * sp32;                        //  4,194,304 (8MB)
  bf16* r64 = c32 + 2L * 64 * sp32;                        // 16,777,216 (32MB)
  bf16* c64 = r64 + 2L * 32 * sp64;                        // 33,554,432 (64MB)
  float* stm = (float*)(c64 + 2L * 64 * sp64);             // 128 f32
  float* stv = stm + 128;

  float* out_cl  = (float*)d_out;                 // 2*2*sp64
  float* out_rec = (float*)d_out + 2L * 2 * sp64; // 2*16*sp64

  // ---- encoder ----
  {
    long tot = 2L * 32 * sp64;
    conv3d_k<float, bf16><<<cdiv_l(tot, TPB), TPB, 0, stream>>>(x, w0, s1, N, 16, 32, 64, 64, 1);
    bn_stats_k<<<32, TPB, 0, stream>>>(s1, stm, stv, N, 32, sp64);
    bn_relu_k<<<2048, TPB, 0, stream>>>(s1, stm, stv, g0, b0, N, 32, sp64);
  }
  {
    long tot = 2L * 64 * sp32;
    conv3d_k<bf16, bf16><<<cdiv_l(tot, TPB), TPB, 0, stream>>>(s1, w1, s2, N, 32, 64, 64, 32, 2);
    bn_stats_k<<<64, TPB, 0, stream>>>(s2, stm, stv, N, 64, sp32);
    bn_relu_k<<<2048, TPB, 0, stream>>>(s2, stm, stv, g1, b1, N, 64, sp32);
  }
  {
    long tot = 2L * 128 * sp16;
    conv3d_k<bf16, bf16><<<cdiv_l(tot, TPB), TPB, 0, stream>>>(s2, w2, s4, N, 64, 128, 32, 16, 2);
    bn_stats_k<<<128, TPB, 0, stream>>>(s4, stm, stv, N, 128, sp16);
    bn_relu_k<<<2048, TPB, 0, stream>>>(s4, stm, stv, g2, b2, N, 128, sp16);
  }

  // ---- level-2 tconvs (16 -> 32) ----
  {
    long tot = 2L * 64 * sp32;
    tconv3d_s2_k<bf16><<<cdiv_l(tot, TPB), TPB, 0, stream>>>(s4, 128, nullptr, 0, wt2r, r32, N, 64, 16, 32);
    bn_stats_k<<<64, TPB, 0, stream>>>(r32, stm, stv, N, 64, sp32);
    bn_relu_k<<<2048, TPB, 0, stream>>>(r32, stm, stv, g2r, b2r, N, 64, sp32);

    tconv3d_s2_k<bf16><<<cdiv_l(tot, TPB), TPB, 0, stream>>>(s4, 128, nullptr, 0, wt2c, c32, N, 64, 16, 32);
    bn_stats_k<<<64, TPB, 0, stream>>>(c32, stm, stv, N, 64, sp32);
    bn_relu_k<<<2048, TPB, 0, stream>>>(c32, stm, stv, g2c, b2c, N, 64, sp32);
  }

  // ---- level-1 tconvs (32 -> 64); cl input = concat(c32, s2) ----
  {
    long totR = 2L * 32 * sp64;
    tconv3d_s2_k<bf16><<<cdiv_l(totR, TPB), TPB, 0, stream>>>(r32, 64, nullptr, 0, wt1r, r64, N, 32, 32, 64);
    bn_stats_k<<<32, TPB, 0, stream>>>(r64, stm, stv, N, 32, sp64);
    bn_relu_k<<<2048, TPB, 0, stream>>>(r64, stm, stv, g1r, b1r, N, 32, sp64);

    long totC = 2L * 64 * sp64;
    tconv3d_s2_k<bf16><<<cdiv_l(totC, TPB), TPB, 0, stream>>>(c32, 64, s2, 64, wt1c, c64, N, 64, 32, 64);
    bn_stats_k<<<64, TPB, 0, stream>>>(c64, stm, stv, N, 64, sp64);
    bn_relu_k<<<2048, TPB, 0, stream>>>(c64, stm, stv, g1c, b1c, N, 64, sp64);
  }

  // ---- level-0 tconvs (stride 1, no BN) -> fp32 outputs ----
  {
    long totR = 2L * 16 * sp64;
    tconv3d_s1_k<float><<<cdiv_l(totR, TPB), TPB, 0, stream>>>(r64, 32, nullptr, 0, wt0r, out_rec, N, 16, 64);
    long totC = 2L * 2 * sp64;
    tconv3d_s1_k<float><<<cdiv_l(totC, TPB), TPB, 0, stream>>>(c64, 64, s1, 32, wt0c, out_cl, N, 2, 64);
  }
}

// Round 3
// 3721.898 us; speedup vs baseline: 7.0589x; 7.0589x over previous
//
#include <hip/hip_runtime.h>
#include <hip/hip_bf16.h>

// ---------------------------------------------------------------------------
// UNet3D dense forward, round 3: register-blocked direct convs.
//  - each thread: 1 output point x CT output channels (CT acc in VGPRs)
//  - weights repacked to [tap][ci][co] so inner-loop weight reads are
//    wave-uniform (scalar loads, sgpr-operand FMAs); input read once per
//    (tap,ci), reused across CT FMAs.
//  - stride-2 tconv decomposed into 8 output-parity octants (uniform taps).
//  - bf16 activations (fp32 accumulate), virtual concats via split inputs.
// ---------------------------------------------------------------------------

using bf16 = __hip_bfloat16;
using ushort8 = unsigned short __attribute__((ext_vector_type(8)));

#define TPB 256

static inline int cdiv_l(long a, int b){ return (int)((a + b - 1) / b); }

__device__ __forceinline__ float b2f(unsigned short u){
  union { unsigned int i; float f; } v; v.i = ((unsigned int)u) << 16; return v.f;
}
__device__ __forceinline__ unsigned short f2b(float f){
  bf16 h = __float2bfloat16(f);
  union { bf16 h; unsigned short u; } v; v.h = h; return v.u;
}
__device__ __forceinline__ float toF(float v){ return v; }
__device__ __forceinline__ float toF(bf16 v){ return __bfloat162float(v); }

// ---------------- weight repack: OIDHW -> [tap][ci][co] ----------------
__global__ void repack_k(const float* __restrict__ w, float* __restrict__ wt,
                         int Cin, int Cout){
  int idx = blockIdx.x * blockDim.x + threadIdx.x;
  int tot = 27 * Cin * Cout;
  if (idx >= tot) return;
  int co = idx % Cout; int t = idx / Cout;
  int ci = t % Cin;    int tap = t / Cin;
  wt[idx] = w[((long)co * Cin + ci) * 27 + tap];
}

// ---------------- conv3d (stride s, pad 1), weights [tap][ci][co] ----------
template <typename Tin, int CT>
__global__ void convA_k(const Tin* __restrict__ in, const float* __restrict__ wt,
                        bf16* __restrict__ out, int N, int Cin, int Cout,
                        int Din, int Dout, int stride) {
  long pts = (long)N * Dout * Dout * Dout;
  long p = (long)blockIdx.x * blockDim.x + threadIdx.x;
  if (p >= pts) return;
  int ow = (int)(p % Dout); long t = p / Dout;
  int oh = (int)(t % Dout); t /= Dout;
  int od = (int)(t % Dout);
  int n  = (int)(t / Dout);
  int co0 = blockIdx.y * CT;
  long sp = (long)Din * Din * Din;
  const Tin* inN = in + (long)n * Cin * sp;

  float acc[CT];
#pragma unroll
  for (int i = 0; i < CT; ++i) acc[i] = 0.f;

  int id0 = od * stride - 1, ih0 = oh * stride - 1, iw0 = ow * stride - 1;
#pragma unroll
  for (int kd = 0; kd < 3; ++kd) {
    int id = id0 + kd; bool vd = (unsigned)id < (unsigned)Din;
#pragma unroll
    for (int kh = 0; kh < 3; ++kh) {
      int ih = ih0 + kh; bool vh = vd && ((unsigned)ih < (unsigned)Din);
#pragma unroll
      for (int kw = 0; kw < 3; ++kw) {
        int iw = iw0 + kw; bool v = vh && ((unsigned)iw < (unsigned)Din);
        int tap = (kd * 3 + kh) * 3 + kw;
        const Tin* ip = inN + (((long)id * Din + ih) * Din + iw);
        const float* wp = wt + (long)tap * Cin * Cout + co0;
#pragma unroll 2
        for (int ci = 0; ci < Cin; ++ci) {
          float in_v = 0.f;
          if (v) in_v = toF(ip[(long)ci * sp]);
          const float* wr = wp + (long)ci * Cout;
#pragma unroll
          for (int co = 0; co < CT; ++co) acc[co] += in_v * wr[co];
        }
      }
    }
  }
  long spo = (long)Dout * Dout * Dout;
  long obase = ((long)n * Cout + co0) * spo + (((long)od * Dout + oh) * Dout + ow);
#pragma unroll
  for (int co = 0; co < CT; ++co) out[obase + (long)co * spo] = __float2bfloat16(acc[co]);
}

// ---------------- tconv3d stride2 'SAME', octant form, weights [tap][ci][co]
// grid.z = octant (pd,ph,pw); output o = 2*oH + p; input i = oH + delta,
// delta per (p,k): p==0 -> k in {0,2}, delta {-1,0}; p==1 -> k=1, delta 0.
template <int CT>
__global__ void tconvA_s2_k(const bf16* __restrict__ inA, int CA,
                            const bf16* __restrict__ inB, int CB,
                            const float* __restrict__ w,
                            bf16* __restrict__ out, int N, int Cout, int Din) {
  int Dout = 2 * Din;
  long pts = (long)N * Din * Din * Din;
  long p = (long)blockIdx.x * blockDim.x + threadIdx.x;
  if (p >= pts) return;
  int oct = blockIdx.z;
  int pd = (oct >> 2) & 1, ph = (oct >> 1) & 1, pw = oct & 1;
  int owH = (int)(p % Din); long t = p / Din;
  int ohH = (int)(t % Din); t /= Din;
  int odH = (int)(t % Din);
  int n   = (int)(t / Din);
  int co0 = blockIdx.y * CT;
  int Cin = CA + CB;
  long sp = (long)Din * Din * Din;
  const bf16* bA = inA + (long)n * CA * sp;
  const bf16* bB = inB ? inB + (long)n * CB * sp : nullptr;

  float acc[CT];
#pragma unroll
  for (int i = 0; i < CT; ++i) acc[i] = 0.f;

  int nkd = pd ? 1 : 2, kds[2], dds[2];
  if (pd) { kds[0] = 1; dds[0] = 0; } else { kds[0] = 0; dds[0] = -1; kds[1] = 2; dds[1] = 0; }
  int nkh = ph ? 1 : 2, khs[2], dhs[2];
  if (ph) { khs[0] = 1; dhs[0] = 0; } else { khs[0] = 0; dhs[0] = -1; khs[1] = 2; dhs[1] = 0; }
  int nkw = pw ? 1 : 2, kws[2], dws[2];
  if (pw) { kws[0] = 1; dws[0] = 0; } else { kws[0] = 0; dws[0] = -1; kws[1] = 2; dws[1] = 0; }

  for (int a = 0; a < nkd; ++a) {
    int id = odH + dds[a]; bool vd = (unsigned)id < (unsigned)Din;
    for (int b = 0; b < nkh; ++b) {
      int ih = ohH + dhs[b]; bool vh = vd && ((unsigned)ih < (unsigned)Din);
      for (int c = 0; c < nkw; ++c) {
        int iw = owH + dws[c]; bool v = vh && ((unsigned)iw < (unsigned)Din);
        int tap = (kds[a] * 3 + khs[b]) * 3 + kws[c];
        long off = ((long)id * Din + ih) * Din + iw;
        const float* wp = w + (long)tap * Cin * Cout + co0;
#pragma unroll 2
        for (int ci = 0; ci < CA; ++ci) {
          float in_v = 0.f;
          if (v) in_v = toF(bA[(long)ci * sp + off]);
          const float* wr = wp + (long)ci * Cout;
#pragma unroll
          for (int co = 0; co < CT; ++co) acc[co] += in_v * wr[co];
        }
        if (bB) {
#pragma unroll 2
          for (int ci = 0; ci < CB; ++ci) {
            float in_v = 0.f;
            if (v) in_v = toF(bB[(long)ci * sp + off]);
            const float* wr = wp + (long)(CA + ci) * Cout;
#pragma unroll
            for (int co = 0; co < CT; ++co) acc[co] += in_v * wr[co];
          }
        }
      }
    }
  }
  long spo = (long)Dout * Dout * Dout;
  int od = 2 * odH + pd, oh = 2 * ohH + ph, ow = 2 * owH + pw;
  long obase = ((long)n * Cout + co0) * spo + (((long)od * Dout + oh) * Dout + ow);
#pragma unroll
  for (int co = 0; co < CT; ++co) out[obase + (long)co * spo] = __float2bfloat16(acc[co]);
}

// ---------------- tconv3d stride1 'SAME' (== conv pad1, DHWIO weights) -----
template <int CT, typename Tout>
__global__ void tconvA_s1_k(const bf16* __restrict__ inA, int CA,
                            const bf16* __restrict__ inB, int CB,
                            const float* __restrict__ w,
                            Tout* __restrict__ out, int N, int Cout, int Din) {
  int Dout = Din;
  long pts = (long)N * Dout * Dout * Dout;
  long p = (long)blockIdx.x * blockDim.x + threadIdx.x;
  if (p >= pts) return;
  int ow = (int)(p % Dout); long t = p / Dout;
  int oh = (int)(t % Dout); t /= Dout;
  int od = (int)(t % Dout);
  int n  = (int)(t / Dout);
  int co0 = blockIdx.y * CT;
  int Cin = CA + CB;
  long sp = (long)Din * Din * Din;
  const bf16* bA = inA + (long)n * CA * sp;
  const bf16* bB = inB ? inB + (long)n * CB * sp : nullptr;

  float acc[CT];
#pragma unroll
  for (int i = 0; i < CT; ++i) acc[i] = 0.f;

#pragma unroll
  for (int kd = 0; kd < 3; ++kd) {
    int id = od + kd - 1; bool vd = (unsigned)id < (unsigned)Din;
#pragma unroll
    for (int kh = 0; kh < 3; ++kh) {
      int ih = oh + kh - 1; bool vh = vd && ((unsigned)ih < (unsigned)Din);
#pragma unroll
      for (int kw = 0; kw < 3; ++kw) {
        int iw = ow + kw - 1; bool v = vh && ((unsigned)iw < (unsigned)Din);
        int tap = (kd * 3 + kh) * 3 + kw;
        long off = ((long)id * Din + ih) * Din + iw;
        const float* wp = w + (long)tap * Cin * Cout + co0;
#pragma unroll 2
        for (int ci = 0; ci < CA; ++ci) {
          float in_v = 0.f;
          if (v) in_v = toF(bA[(long)ci * sp + off]);
          const float* wr = wp + (long)ci * Cout;
#pragma unroll
          for (int co = 0; co < CT; ++co) acc[co] += in_v * wr[co];
        }
        if (bB) {
#pragma unroll 2
          for (int ci = 0; ci < CB; ++ci) {
            float in_v = 0.f;
            if (v) in_v = toF(bB[(long)ci * sp + off]);
            const float* wr = wp + (long)(CA + ci) * Cout;
#pragma unroll
            for (int co = 0; co < CT; ++co) acc[co] += in_v * wr[co];
          }
        }
      }
    }
  }
  long spo = (long)Dout * Dout * Dout;
  long obase = ((long)n * Cout + co0) * spo + (((long)od * Dout + oh) * Dout + ow);
#pragma unroll
  for (int co = 0; co < CT; ++co) {
    float y = acc[co];
    if constexpr (sizeof(Tout) == 2) out[obase + (long)co * spo] = (Tout)__float2bfloat16(y);
    else out[obase + (long)co * spo] = y;
  }
}

// ---------------- BN stats stage 1: per (channel, chunk) partial sums ------
__global__ void bn_stats1_k(const unsigned short* __restrict__ x, float* __restrict__ part,
                            int N, int C, long sp, int lsp, int K) {
  int c = blockIdx.x, ch = blockIdx.y, tid = threadIdx.x;
  long tot = (long)N * sp;
  float s = 0.f, q = 0.f;
  for (long e = ((long)ch * TPB + tid) * 8; e < tot; e += (long)K * TPB * 8) {
    int n = (int)(e >> lsp);
    long i = e & (sp - 1);
    const ushort8 vv = *(const ushort8*)(x + ((long)n * C + c) * sp + i);
#pragma unroll
    for (int j = 0; j < 8; ++j) { float f = b2f(vv[j]); s += f; q += f * f; }
  }
  __shared__ float shs[TPB], shq[TPB];
  shs[tid] = s; shq[tid] = q;
  __syncthreads();
  for (int off = TPB / 2; off > 0; off >>= 1) {
    if (tid < off) { shs[tid] += shs[tid + off]; shq[tid] += shq[tid + off]; }
    __syncthreads();
  }
  if (tid == 0) { part[((long)c * K + ch) * 2] = shs[0]; part[((long)c * K + ch) * 2 + 1] = shq[0]; }
}

// ---------------- BN stats stage 2: reduce partials -> scale/shift ---------
__global__ void bn_stats2_k(const float* __restrict__ part, const float* __restrict__ g,
                            const float* __restrict__ b, float* __restrict__ scale,
                            float* __restrict__ shift, int C, int K, float inv_cnt) {
  int c = blockIdx.x * blockDim.x + threadIdx.x;
  if (c >= C) return;
  float s = 0.f, q = 0.f;
  for (int k = 0; k < K; ++k) { s += part[((long)c * K + k) * 2]; q += part[((long)c * K + k) * 2 + 1]; }
  float m = s * inv_cnt, v = q * inv_cnt - m * m;
  float rs = rsqrtf(v + 1e-5f) * g[c];
  scale[c] = rs;
  shift[c] = b[c] - m * rs;
}

// ---------------- BN apply + ReLU (vectorized, in place) -------------------
__global__ void bn_relu_k(unsigned short* __restrict__ x, const float* __restrict__ scale,
                          const float* __restrict__ shift, int C, int lsp, long tot8) {
  long i8 = (long)blockIdx.x * blockDim.x + threadIdx.x;
  if (i8 >= tot8) return;
  long e = i8 * 8;
  int c = (int)((e >> lsp) % C);
  float sc = scale[c], sh = shift[c];
  ushort8 v = *(ushort8*)(x + e);
  ushort8 r;
#pragma unroll
  for (int j = 0; j < 8; ++j) {
    float y = b2f(v[j]) * sc + sh;
    r[j] = f2b(y > 0.f ? y : 0.f);
  }
  *(ushort8*)(x + e) = r;
}

extern "C" void kernel_launch(void* const* d_in, const int* in_sizes, int n_in,
                              void* d_out, int out_size, void* d_ws, size_t ws_size,
                              hipStream_t stream) {
  const float* x    = (const float*)d_in[0];
  const float* w0   = (const float*)d_in[1];
  const float* g0   = (const float*)d_in[2];
  const float* b0   = (const float*)d_in[3];
  const float* w1   = (const float*)d_in[4];
  const float* g1   = (const float*)d_in[5];
  const float* b1   = (const float*)d_in[6];
  const float* w2   = (const float*)d_in[7];
  const float* g2   = (const float*)d_in[8];
  const float* b2   = (const float*)d_in[9];
  const float* wt2r = (const float*)d_in[10];
  const float* g2r  = (const float*)d_in[11];
  const float* b2r  = (const float*)d_in[12];
  const float* wt1r = (const float*)d_in[13];
  const float* g1r  = (const float*)d_in[14];
  const float* b1r  = (const float*)d_in[15];
  const float* wt0r = (const float*)d_in[16];
  const float* wt2c = (const float*)d_in[17];
  const float* g2c  = (const float*)d_in[18];
  const float* b2c  = (const float*)d_in[19];
  const float* wt1c = (const float*)d_in[20];
  const float* g1c  = (const float*)d_in[21];
  const float* b1c  = (const float*)d_in[22];
  const float* wt0c = (const float*)d_in[23];

  const int N = 2;
  const long sp64 = 64L * 64 * 64, sp32 = 32L * 32 * 32, sp16 = 16L * 16 * 16;
  const int K = 8;  // bn chunks

  // ---- workspace layout ----
  bf16* s1  = (bf16*)d_ws;                  // 16,777,216
  bf16* s2  = s1  + 2L * 32 * sp64;         //  4,194,304
  bf16* s4  = s2  + 2L * 64 * sp32;         //  1,048,576
  bf16* r32 = s4  + 2L * 128 * sp16;        //  4,194,304
  bf16* c32 = r32 + 2L * 64 * sp32;         //  4,194,304
  bf16* r64 = c32 + 2L * 64 * sp32;         // 16,777,216
  bf16* c64 = r64 + 2L * 32 * sp64;         // 33,554,432
  float* wtp0 = (float*)(c64 + 2L * 64 * sp64);  // 27*16*32 = 13,824
  float* wtp1 = wtp0 + 27L * 16 * 32;            // 27*32*64 = 55,296
  float* wtp2 = wtp1 + 27L * 32 * 64;            // 27*64*128 = 221,184
  float* part = wtp2 + 27L * 64 * 128;           // 128*K*2 = 2048
  float* bsc  = part + 128L * K * 2;             // 128
  float* bsh  = bsc + 128;                       // 128

  float* out_cl  = (float*)d_out;
  float* out_rec = (float*)d_out + 2L * 2 * sp64;

  // ---- repack encoder weights ----
  repack_k<<<cdiv_l(27L * 16 * 32, TPB), TPB, 0, stream>>>(w0, wtp0, 16, 32);
  repack_k<<<cdiv_l(27L * 32 * 64, TPB), TPB, 0, stream>>>(w1, wtp1, 32, 64);
  repack_k<<<cdiv_l(27L * 64 * 128, TPB), TPB, 0, stream>>>(w2, wtp2, 64, 128);

  auto bn = [&](bf16* tens, const float* g, const float* b, int C, long sp, int lsp) {
    bn_stats1_k<<<dim3((unsigned)C, K), TPB, 0, stream>>>((unsigned short*)tens, part, N, C, sp, lsp, K);
    bn_stats2_k<<<1, 128, 0, stream>>>(part, g, b, bsc, bsh, C, K, 1.f / (float)(N * sp));
    long tot8 = (long)N * C * sp / 8;
    bn_relu_k<<<cdiv_l(tot8, TPB), TPB, 0, stream>>>((unsigned short*)tens, bsc, bsh, C, lsp, tot8);
  };

  // ---- encoder ----
  convA_k<float, 32><<<dim3(cdiv_l(2L * sp64, TPB), 1), TPB, 0, stream>>>(x, wtp0, s1, N, 16, 32, 64, 64, 1);
  bn(s1, g0, b0, 32, sp64, 18);
  convA_k<bf16, 32><<<dim3(cdiv_l(2L * sp32, TPB), 2), TPB, 0, stream>>>(s1, wtp1, s2, N, 32, 64, 64, 32, 2);
  bn(s2, g1, b1, 64, sp32, 15);
  convA_k<bf16, 16><<<dim3(cdiv_l(2L * sp16, TPB), 8), TPB, 0, stream>>>(s2, wtp2, s4, N, 64, 128, 32, 16, 2);
  bn(s4, g2, b2, 128, sp16, 12);

  // ---- level-2 tconvs (16 -> 32) ----
  tconvA_s2_k<32><<<dim3(cdiv_l(2L * sp16, TPB), 2, 8), TPB, 0, stream>>>(s4, 128, nullptr, 0, wt2r, r32, N, 64, 16);
  bn(r32, g2r, b2r, 64, sp32, 15);
  tconvA_s2_k<32><<<dim3(cdiv_l(2L * sp16, TPB), 2, 8), TPB, 0, stream>>>(s4, 128, nullptr, 0, wt2c, c32, N, 64, 16);
  bn(c32, g2c, b2c, 64, sp32, 15);

  // ---- level-1 tconvs (32 -> 64) ----
  tconvA_s2_k<32><<<dim3(cdiv_l(2L * sp32, TPB), 1, 8), TPB, 0, stream>>>(r32, 64, nullptr, 0, wt1r, r64, N, 32, 32);
  bn(r64, g1r, b1r, 32, sp64, 18);
  tconvA_s2_k<32><<<dim3(cdiv_l(2L * sp32, TPB), 2, 8), TPB, 0, stream>>>(c32, 64, s2, 64, wt1c, c64, N, 64, 32);
  bn(c64, g1c, b1c, 64, sp64, 18);

  // ---- level-0 tconvs (stride 1, no BN) -> fp32 outputs ----
  tconvA_s1_k<16, float><<<dim3(cdiv_l(2L * sp64, TPB), 1), TPB, 0, stream>>>(r64, 32, nullptr, 0, wt0r, out_rec, N, 16, 64);
  tconvA_s1_k<2, float><<<dim3(cdiv_l(2L * sp64, TPB), 1), TPB, 0, stream>>>(c64, 64, s1, 32, wt0c, out_cl, N, 2, 64);
}